// Round 9
// baseline (686.260 us; speedup 1.0000x reference)
//
#include <hip/hip_runtime.h>
#include <hip/hip_bf16.h>
#include <stdint.h>

// Problem dims (fixed by reference): B=64, T=512, H=1024, A=300
#define B_DIM 64
#define T_DIM 512
#define H_DIM 1024
#define K_DIM 1024
#define M_DIM (B_DIM * T_DIM)

typedef int i32x4 __attribute__((ext_vector_type(4)));
typedef int i32x8 __attribute__((ext_vector_type(8)));
typedef float f32x2 __attribute__((ext_vector_type(2)));
typedef float f32x4 __attribute__((ext_vector_type(4)));

__device__ __forceinline__ float tanh_fast(float x) {
  float e = __expf(2.0f * x);
  return 1.0f - 2.0f / (e + 1.0f);
}

// async global->LDS, 16B per lane. LDS dest must be wave-uniform base + lane*16.
__device__ __forceinline__ void async_cp16(const void* gp, void* lp) {
  __builtin_amdgcn_global_load_lds(
      reinterpret_cast<const __attribute__((address_space(1))) uint32_t*>(
          reinterpret_cast<uintptr_t>(gp)),
      reinterpret_cast<__attribute__((address_space(3))) uint32_t*>(
          reinterpret_cast<uintptr_t>(lp)),
      16, 0, 0);
}

// ---------- cvt hidden fp32 -> fp8 e4m3, scaled x16 (std 1.0 -> 16) ----------
__global__ void cvt_hidden_kernel(const float* __restrict__ src, int* __restrict__ dst) {
  int i = blockIdx.x * 256 + threadIdx.x;  // one dword = 4 fp8
  float4 v = reinterpret_cast<const float4*>(src)[i];
  int d = __builtin_amdgcn_cvt_pk_fp8_f32(v.x * 16.f, v.y * 16.f, 0, false);
  d = __builtin_amdgcn_cvt_pk_fp8_f32(v.z * 16.f, v.w * 16.f, d, true);
  dst[i] = d;
}

// ---- cvt W_h (x32) -> fp8 (1024 blocks) + zero scores (32) + zero r (64) ----
__global__ void cvtW_zero_kernel(const float* __restrict__ Wh, int* __restrict__ whF8,
                                 float* __restrict__ scores, float* __restrict__ r) {
  int bid = blockIdx.x, tid = threadIdx.x;
  if (bid < 1024) {
    int i = bid * 256 + tid;
    float4 v = reinterpret_cast<const float4*>(Wh)[i];
    int d = __builtin_amdgcn_cvt_pk_fp8_f32(v.x * 32.f, v.y * 32.f, 0, false);
    d = __builtin_amdgcn_cvt_pk_fp8_f32(v.z * 32.f, v.w * 32.f, d, true);
    whF8[i] = d;
  } else if (bid < 1056) {
    int i = (bid - 1024) * 256 + tid;   // scores: 32768 floats = 8192 float4
    reinterpret_cast<float4*>(scores)[i] = make_float4(0.f, 0.f, 0.f, 0.f);
  } else {
    int i = (bid - 1056) * 256 + tid;   // r: 65536 floats = 16384 float4 (64 blocks)
    reinterpret_cast<float4*>(r)[i] = make_float4(0.f, 0.f, 0.f, 0.f);
  }
}

// ---------------- fused fp8-MX GEMM + tanh + dot(w_w) -> scores ----------------
// R9: 16x16x128 scaled MFMA (same fp8-MX rate as 32x32x64, m21) so the acc is
// f32x4-chunked (R6's allocator-friendly shape) instead of rigid f32x16 tuples
// (R7/R8 spill: VGPR capped at 128 by the 128-AGPR acc, f32x16 blew the arch
// side -> 490MB scratch). Block 256Mx128N, 4 waves 2m x 2n each 128x64 =
// 8mi x 4ni 16x16 tiles; acc[8][4] f32x4 = 128 f32. K=128/inst -> 8 K-iters.
// Frag k-map (generalizing HW-verified R7 + m89): A[m=lane&15][k=quad*32+byte];
// C/D (m89-verified, dtype-indep): col=lane&15, row=quad*4+reg.
// LDS split-plane layout (R7/R8: measured 0 conflicts): A chunk(kc,row) at
// kc*4096+row*16 (8 planes), B at kc*2048+row*16. Scales 2^-4/2^-5 (e8m0
// 123/122) recover hidden.W_h exactly. XCD swizzle m=bid&127, n=bid>>7.
__global__ __launch_bounds__(256, 2) void gemm_scores_kernel(
    const uint8_t* __restrict__ Af8, const uint8_t* __restrict__ Bf8,
    const float* __restrict__ bh, const float* __restrict__ ww,
    float* __restrict__ scores) {
  __shared__ __attribute__((aligned(16))) uint8_t lA[256 * 128];  // 32 KB
  __shared__ __attribute__((aligned(16))) uint8_t lB[128 * 128];  // 16 KB

  const int tid = threadIdx.x;
  const int bid = blockIdx.x;
  const int m0 = (bid & 127) * 256;
  const int n0 = (bid >> 7) * 128;

  const int wv = tid >> 6;
  const int lane = tid & 63;
  const int wm = wv & 1, wn = wv >> 1;   // waves 2m x 2n, each 128x64
  const int r16 = lane & 15, quad = lane >> 4;

  f32x4 acc[8][4] = {};

  // A staging: 8 chunks/thread; chunk c = j*256+tid -> kc=j (plane), row=tid.
  //   global = Af8[(m0+tid)*K + k0 + j*16], LDS = lA + j*4096 + tid*16.
  const uint8_t* gA = Af8 + (size_t)(m0 + tid) * K_DIM;
  uint8_t* lAbase = &lA[tid * 16];
  // B staging: 4 chunks/thread; c = j*256+tid -> kc = 2j+(tid>>7), row = tid&127.
  const uint8_t* gB[4]; uint8_t* lBd[4];
#pragma unroll
  for (int j = 0; j < 4; ++j) {
    int c = j * 256 + tid;
    int row = c & 127, kc = c >> 7;
    gB[j] = Bf8 + (size_t)(n0 + row) * K_DIM + kc * 16;
    lBd[j] = &lB[c * 16];
  }

  // fragment LDS bases: lane's 32B = planes (2q, 2q+1); lo at base, hi +plane.
  const uint8_t* paf = &lA[(2 * quad) * 4096 + (wm * 128 + r16) * 16];
  const uint8_t* pbf = &lB[(2 * quad) * 2048 + (wn * 64 + r16) * 16];

#pragma unroll
  for (int k0 = 0; k0 < K_DIM; k0 += 128) {
#pragma unroll
    for (int j = 0; j < 8; ++j) async_cp16(gA + (k0 + j * 16), lAbase + j * 4096);
#pragma unroll
    for (int j = 0; j < 4; ++j) async_cp16(gB[j] + k0, lBd[j]);
    __syncthreads();

    i32x8 bfr[4];
#pragma unroll
    for (int ni = 0; ni < 4; ++ni) {
      i32x4 lo = *reinterpret_cast<const i32x4*>(pbf + ni * 256);
      i32x4 hi = *reinterpret_cast<const i32x4*>(pbf + ni * 256 + 2048);
      bfr[ni] = __builtin_shufflevector(lo, hi, 0, 1, 2, 3, 4, 5, 6, 7);
    }
#pragma unroll
    for (int mi = 0; mi < 8; ++mi) {
      i32x4 lo = *reinterpret_cast<const i32x4*>(paf + mi * 256);
      i32x4 hi = *reinterpret_cast<const i32x4*>(paf + mi * 256 + 4096);
      i32x8 af = __builtin_shufflevector(lo, hi, 0, 1, 2, 3, 4, 5, 6, 7);
#pragma unroll
      for (int ni = 0; ni < 4; ++ni)
        acc[mi][ni] = __builtin_amdgcn_mfma_scale_f32_16x16x128_f8f6f4(
            af, bfr[ni], acc[mi][ni], 0, 0,
            0, 0x7B7B7B7B,   // A scale: e8m0 123 = 2^-4
            0, 0x7A7A7A7A);  // B scale: e8m0 122 = 2^-5
    }
    __syncthreads();
  }

  // epilogue: C/D 16x16 layout col=lane&15, row=quad*4+reg (m89-verified)
  float bhv[4], wwv[4];
#pragma unroll
  for (int ni = 0; ni < 4; ++ni) {
    int n = n0 + wn * 64 + ni * 16 + r16;
    bhv[ni] = bh[n];
    wwv[ni] = ww[n];
  }
#pragma unroll
  for (int mi = 0; mi < 8; ++mi) {
#pragma unroll
    for (int rg = 0; rg < 4; ++rg) {
      float s = 0.f;
#pragma unroll
      for (int ni = 0; ni < 4; ++ni)
        s += tanh_fast(acc[mi][ni][rg] + bhv[ni]) * wwv[ni];
      s += __shfl_xor(s, 1, 16);
      s += __shfl_xor(s, 2, 16);
      s += __shfl_xor(s, 4, 16);
      s += __shfl_xor(s, 8, 16);
      if (r16 == 0) {
        int m = m0 + wm * 128 + mi * 16 + quad * 4 + rg;
        atomicAdd(&scores[m], s);
      }
    }
  }
}

// ------- fused softmax (recomputed per block) + weighted sum r (512 blocks) -------
// reads fp8 hidden copy (x16 scale folded out at the end)
__global__ void wsum_kernel(const float* __restrict__ scores,
                            const uint8_t* __restrict__ hidF8,
                            float* __restrict__ r) {
  __shared__ float al[64];
  __shared__ float red[8];
  const int bid = blockIdx.x, tid = threadIdx.x;
  const int b = bid >> 3, tc = bid & 7;
  const int wv = tid >> 6, lane = tid & 63;
  float v0 = scores[b * T_DIM + tid];
  float v1 = scores[b * T_DIM + 256 + tid];
  float mx = fmaxf(v0, v1);
#pragma unroll
  for (int off = 1; off < 64; off <<= 1) mx = fmaxf(mx, __shfl_xor(mx, off, 64));
  if (lane == 0) red[wv] = mx;
  __syncthreads();
  mx = fmaxf(fmaxf(red[0], red[1]), fmaxf(red[2], red[3]));
  float e0 = __expf(v0 - mx), e1 = __expf(v1 - mx);
  float s = e0 + e1;
#pragma unroll
  for (int off = 1; off < 64; off <<= 1) s += __shfl_xor(s, off, 64);
  if (lane == 0) red[4 + wv] = s;
  __syncthreads();
  float inv = 1.0f / (red[4] + red[5] + red[6] + red[7]);
  if (tid < 64) al[tid] = __expf(scores[b * T_DIM + tc * 64 + tid] - mx) * inv;
  __syncthreads();
  const int* hp = reinterpret_cast<const int*>(hidF8) +
                  ((size_t)b * T_DIM * H_DIM + (size_t)tc * 64 * H_DIM) / 4 + tid;
  float4 acc = make_float4(0.f, 0.f, 0.f, 0.f);
#pragma unroll 8
  for (int t = 0; t < 64; ++t) {
    float a = al[t];
    int u = hp[t * (H_DIM / 4)];
    f32x2 lo = __builtin_amdgcn_cvt_pk_f32_fp8(u, false);
    f32x2 hi = __builtin_amdgcn_cvt_pk_f32_fp8(u, true);
    acc.x += a * lo[0];
    acc.y += a * lo[1];
    acc.z += a * hi[0];
    acc.w += a * hi[1];
  }
  float* rp = r + b * H_DIM + tid * 4;
  atomicAdd(rp + 0, acc.x * 0.0625f);
  atomicAdd(rp + 1, acc.y * 0.0625f);
  atomicAdd(rp + 2, acc.z * 0.0625f);
  atomicAdd(rp + 3, acc.w * 0.0625f);
}

// ---------------- dst[i,h] = bias[h] + src_row_i . W[h,:] ----------------
// grid (H/64, B) = 1024 blocks; 4 lanes split K per output h; shfl-reduce.
__global__ void rowvec_matT_kernel(const float* __restrict__ src, size_t src_stride,
                                   const float* __restrict__ W, const float* __restrict__ bias,
                                   float* __restrict__ dst) {
  __shared__ float sv[H_DIM];
  const int i = blockIdx.y, h0 = blockIdx.x * 64, tid = threadIdx.x;
  reinterpret_cast<float4*>(sv)[tid] =
      reinterpret_cast<const float4*>(src + (size_t)i * src_stride)[tid];
  __syncthreads();
  const int hl = tid >> 2;
  const int kq = tid & 3;
  const float* wr = W + (size_t)(h0 + hl) * H_DIM + kq * 256;
  const float* svp = sv + kq * 256;
  float acc = 0.f;
#pragma unroll 4
  for (int k = 0; k < 256; k += 4) {
    float4 w4 = *reinterpret_cast<const float4*>(wr + k);
    float4 s4 = *reinterpret_cast<const float4*>(svp + k);
    acc += w4.x * s4.x + w4.y * s4.y + w4.z * s4.z + w4.w * s4.w;
  }
  acc += __shfl_xor(acc, 1, 4);
  acc += __shfl_xor(acc, 2, 4);
  if (kq == 0) dst[(size_t)i * H_DIM + h0 + hl] = acc + bias[h0 + hl];
}

// ---------------- out[i,j,h] = tanh(rp[i,h] + xq[j,h])  [B,B,H] quirk ----------------
__global__ void final_kernel(const float* __restrict__ rp, const float* __restrict__ xq,
                             float* __restrict__ out) {
  int idx = blockIdx.x * 256 + threadIdx.x;
  int e = idx * 4;
  int i = e >> 16;
  int j = (e >> 10) & 63;
  int h = e & 1023;
  float4 a = *reinterpret_cast<const float4*>(&rp[i * H_DIM + h]);
  float4 b = *reinterpret_cast<const float4*>(&xq[j * H_DIM + h]);
  float4 o;
  o.x = tanh_fast(a.x + b.x);
  o.y = tanh_fast(a.y + b.y);
  o.z = tanh_fast(a.z + b.z);
  o.w = tanh_fast(a.w + b.w);
  *reinterpret_cast<float4*>(&out[e]) = o;
}

extern "C" void kernel_launch(void* const* d_in, const int* in_sizes, int n_in,
                              void* d_out, int out_size, void* d_ws, size_t ws_size,
                              hipStream_t stream) {
  const float* hidden = (const float*)d_in[0];
  // aspect (1), W_v (4), b_v (5), w_b (7) cancel under softmax -> unused
  const float* W_h = (const float*)d_in[2];
  const float* b_h = (const float*)d_in[3];
  const float* w_w = (const float*)d_in[6];  // use first H entries
  const float* W_p = (const float*)d_in[8];
  const float* b_p = (const float*)d_in[9];
  const float* W_x = (const float*)d_in[10];
  const float* b_x = (const float*)d_in[11];
  float* out = (float*)d_out;

  char* ws = (char*)d_ws;
  uint8_t* hidF8 = (uint8_t*)ws;                 // 32 MB
  uint8_t* whF8 = (uint8_t*)(ws + 33554432);     // 1 MB
  float* scores = (float*)(ws + 34603008);       // 128 KB
  float* r = (float*)(ws + 34734080);            // 256 KB
  float* rp = (float*)(ws + 34996224);           // 256 KB
  float* xq = (float*)(ws + 35258368);           // 256 KB

  // 1) cvt hidden (x16) -> fp8; cvt W_h (x32) -> fp8 + zero scores/r
  cvt_hidden_kernel<<<32768, 256, 0, stream>>>(hidden, (int*)hidF8);
  cvtW_zero_kernel<<<1120, 256, 0, stream>>>(W_h, (int*)whF8, scores, r);

  // 2) fused fp8-MX GEMM -> scores (256x128 tiles, 1024 blocks, XCD-swizzled)
  gemm_scores_kernel<<<1024, 256, 0, stream>>>(hidF8, whF8, b_h, w_w, scores);

  // 3) softmax + weighted sum (fused, 512 blocks)
  wsum_kernel<<<512, 256, 0, stream>>>(scores, hidF8, r);

  // 4) rp = r @ W_p^T + b_p ; xq = hidden[:,-1,:] @ W_x^T + b_x
  rowvec_matT_kernel<<<dim3(H_DIM / 64, B_DIM), 256, 0, stream>>>(r, (size_t)H_DIM, W_p, b_p, rp);
  rowvec_matT_kernel<<<dim3(H_DIM / 64, B_DIM), 256, 0, stream>>>(
      hidden + (size_t)(T_DIM - 1) * H_DIM, (size_t)T_DIM * H_DIM, W_x, b_x, xq);

  // 5) out[i,j,h] = tanh(rp[i,h] + xq[j,h])
  final_kernel<<<(B_DIM * B_DIM * H_DIM / 4) / 256, 256, 0, stream>>>(rp, xq, out);
}

// Round 10
// 381.867 us; speedup vs baseline: 1.7971x; 1.7971x over previous
//
#include <hip/hip_runtime.h>
#include <hip/hip_bf16.h>
#include <stdint.h>

// Problem dims (fixed by reference): B=64, T=512, H=1024, A=300
#define B_DIM 64
#define T_DIM 512
#define H_DIM 1024
#define K_DIM 1024
#define M_DIM (B_DIM * T_DIM)  // 32768 rows of the big GEMM

typedef __bf16 bf16x8 __attribute__((ext_vector_type(8)));
typedef float f32x4 __attribute__((ext_vector_type(4)));

__device__ __forceinline__ float tanh_fast(float x) {
  float e = __expf(2.0f * x);
  return 1.0f - 2.0f / (e + 1.0f);
}

__device__ __forceinline__ float bf2f(unsigned short u) {
  return __uint_as_float(((unsigned int)u) << 16);
}

// async global->LDS, 16B per lane. LDS dest must be wave-uniform base + lane*16.
__device__ __forceinline__ void async_cp16(const void* gp, void* lp) {
  __builtin_amdgcn_global_load_lds(
      reinterpret_cast<const __attribute__((address_space(1))) uint32_t*>(
          reinterpret_cast<uintptr_t>(gp)),
      reinterpret_cast<__attribute__((address_space(3))) uint32_t*>(
          reinterpret_cast<uintptr_t>(lp)),
      16, 0, 0);
}

// ---------------- fp32 -> bf16 conversion of hidden (32768 blocks) ----------------
__global__ void cvt_hidden_kernel(const float* __restrict__ src, __bf16* __restrict__ dst) {
  int i = blockIdx.x * 256 + threadIdx.x;
  float4 v = reinterpret_cast<const float4*>(src)[i];
  union { __bf16 b[4]; uint2 u; } o;
  o.b[0] = (__bf16)v.x; o.b[1] = (__bf16)v.y; o.b[2] = (__bf16)v.z; o.b[3] = (__bf16)v.w;
  reinterpret_cast<uint2*>(dst)[i] = o.u;
}

// ---- cvt W_h (1024 blocks) + zero scores (32 blocks) + zero r (64 blocks) ----
__global__ void cvtW_zero_kernel(const float* __restrict__ Wh, __bf16* __restrict__ whBf,
                                 float* __restrict__ scores, float* __restrict__ r) {
  int bid = blockIdx.x, tid = threadIdx.x;
  if (bid < 1024) {
    int i = bid * 256 + tid;
    float4 v = reinterpret_cast<const float4*>(Wh)[i];
    union { __bf16 b[4]; uint2 u; } o;
    o.b[0] = (__bf16)v.x; o.b[1] = (__bf16)v.y; o.b[2] = (__bf16)v.z; o.b[3] = (__bf16)v.w;
    reinterpret_cast<uint2*>(whBf)[i] = o.u;
  } else if (bid < 1056) {
    int i = (bid - 1024) * 256 + tid;   // scores: 32768 floats = 8192 float4
    reinterpret_cast<float4*>(scores)[i] = make_float4(0.f, 0.f, 0.f, 0.f);
  } else {
    int i = (bid - 1056) * 256 + tid;   // r: 65536 floats = 16384 float4 (64 blocks)
    reinterpret_cast<float4*>(r)[i] = make_float4(0.f, 0.f, 0.f, 0.f);
  }
}

// ---------------- fused GEMM + tanh + dot(w_w) -> scores (R6, measured 85us) ----
// Block tile 256Mx128N, 4 waves each 128x64 (8x4 acc). Fat wave-tile keeps the
// inner loop MFMA-bound: 24 ds_read_b128 per 64 MFMA.
// LDS: A 32KB + B 16KB, XOR-swizzled (R3/R6-verified conflicts=0). Full K unroll
// folds global offsets into the 13-bit imm of global_load_lds. XCD swizzle:
// m=bid&127, n=bid>>7 (R4/R6-verified FETCH cut to ~87MB).
#define GM_BK 64
__global__ __launch_bounds__(256, 2) void gemm_scores_kernel(
    const __bf16* __restrict__ A, const __bf16* __restrict__ Bm,
    const float* __restrict__ bh, const float* __restrict__ ww,
    float* __restrict__ scores) {
  __shared__ __attribute__((aligned(16))) __bf16 lA[256 * GM_BK];  // 32 KB
  __shared__ __attribute__((aligned(16))) __bf16 lB[128 * GM_BK];  // 16 KB

  const int tid = threadIdx.x;
  const int bid = blockIdx.x;
  const int m0 = (bid & 127) * 256;
  const int n0 = (bid >> 7) * 128;

  const int wv = tid >> 6;
  const int lane = tid & 63;
  const int wm = wv & 1, wn = wv >> 1;           // waves: 2m x 2n, each 128x64
  const int r16 = lane & 15, quad = lane >> 4;

  f32x4 acc[8][4] = {};

  // staging: A 8 chunks/thread, B 4 chunks/thread per K-step
  // chunk (row, p) holds k-chunk kc = p ^ ((row>>1)&7)
  const __bf16* gA[8]; __bf16* lAd[8];
#pragma unroll
  for (int j = 0; j < 8; ++j) {
    int c = j * 256 + tid;
    int row = c >> 3;
    int p = c & 7;
    int kc = p ^ ((row >> 1) & 7);
    gA[j] = A + (size_t)(m0 + row) * K_DIM + kc * 8;
    lAd[j] = &lA[c * 8];
  }
  const __bf16* gB[4]; __bf16* lBd[4];
#pragma unroll
  for (int j = 0; j < 4; ++j) {
    int c = j * 256 + tid;
    int row = c >> 3;
    int p = c & 7;
    int kc = p ^ ((row >> 1) & 7);
    gB[j] = Bm + (size_t)(n0 + row) * K_DIM + kc * 8;
    lBd[j] = &lB[c * 8];
  }

  const int sw = r16 >> 1;
  const __bf16* pa[2]; const __bf16* pb[2];
#pragma unroll
  for (int kk = 0; kk < 2; ++kk) {
    pa[kk] = &lA[(wm * 128 + r16) * GM_BK + ((kk * 4 + quad) ^ sw) * 8];
    pb[kk] = &lB[(wn * 64 + r16) * GM_BK + ((kk * 4 + quad) ^ sw) * 8];
  }

#pragma unroll
  for (int k0 = 0; k0 < K_DIM; k0 += GM_BK) {
#pragma unroll
    for (int j = 0; j < 8; ++j) async_cp16(gA[j] + k0, lAd[j]);
#pragma unroll
    for (int j = 0; j < 4; ++j) async_cp16(gB[j] + k0, lBd[j]);
    __syncthreads();
#pragma unroll
    for (int kk = 0; kk < 2; ++kk) {
      bf16x8 bfr[4];
#pragma unroll
      for (int ni = 0; ni < 4; ++ni)
        bfr[ni] = *reinterpret_cast<const bf16x8*>(pb[kk] + ni * 16 * GM_BK);
      bf16x8 af[8];
#pragma unroll
      for (int mi = 0; mi < 8; ++mi)
        af[mi] = *reinterpret_cast<const bf16x8*>(pa[kk] + mi * 16 * GM_BK);
#pragma unroll
      for (int mi = 0; mi < 8; ++mi)
#pragma unroll
        for (int ni = 0; ni < 4; ++ni)
          acc[mi][ni] = __builtin_amdgcn_mfma_f32_16x16x32_bf16(af[mi], bfr[ni], acc[mi][ni], 0, 0, 0);
    }
    __syncthreads();
  }

  // epilogue: C/D layout col=lane&15, row=quad*4+reg (m89-verified)
  float bhv[4], wwv[4];
#pragma unroll
  for (int ni = 0; ni < 4; ++ni) {
    int n = n0 + wn * 64 + ni * 16 + r16;
    bhv[ni] = bh[n];
    wwv[ni] = ww[n];
  }
#pragma unroll
  for (int mi = 0; mi < 8; ++mi) {
#pragma unroll
    for (int rg = 0; rg < 4; ++rg) {
      float s = 0.f;
#pragma unroll
      for (int ni = 0; ni < 4; ++ni)
        s += tanh_fast(acc[mi][ni][rg] + bhv[ni]) * wwv[ni];
      s += __shfl_xor(s, 1, 16);
      s += __shfl_xor(s, 2, 16);
      s += __shfl_xor(s, 4, 16);
      s += __shfl_xor(s, 8, 16);
      if (r16 == 0) {
        int m = m0 + wm * 128 + mi * 16 + quad * 4 + rg;
        atomicAdd(&scores[m], s);
      }
    }
  }
}

// ------- fused softmax(recomputed per block) + weighted sum r (512 blocks) -------
// block (b = bid>>3, t-chunk = bid&7); bf16 hidden reads (R5-verified).
__global__ void wsum_kernel(const float* __restrict__ scores,
                            const __bf16* __restrict__ hiddenBf,
                            float* __restrict__ r) {
  __shared__ float al[64];
  __shared__ float red[8];
  const int bid = blockIdx.x, tid = threadIdx.x;
  const int b = bid >> 3, tc = bid & 7;
  const int wv = tid >> 6, lane = tid & 63;
  float v0 = scores[b * T_DIM + tid];
  float v1 = scores[b * T_DIM + 256 + tid];
  float mx = fmaxf(v0, v1);
#pragma unroll
  for (int off = 1; off < 64; off <<= 1) mx = fmaxf(mx, __shfl_xor(mx, off, 64));
  if (lane == 0) red[wv] = mx;
  __syncthreads();
  mx = fmaxf(fmaxf(red[0], red[1]), fmaxf(red[2], red[3]));
  float e0 = __expf(v0 - mx), e1 = __expf(v1 - mx);
  float s = e0 + e1;
#pragma unroll
  for (int off = 1; off < 64; off <<= 1) s += __shfl_xor(s, off, 64);
  if (lane == 0) red[4 + wv] = s;
  __syncthreads();
  float inv = 1.0f / (red[4] + red[5] + red[6] + red[7]);
  if (tid < 64) al[tid] = __expf(scores[b * T_DIM + tc * 64 + tid] - mx) * inv;
  __syncthreads();
  const __bf16* hp = hiddenBf + (size_t)b * T_DIM * H_DIM + (size_t)tc * 64 * H_DIM + tid * 4;
  float4 acc = make_float4(0.f, 0.f, 0.f, 0.f);
#pragma unroll 8
  for (int t = 0; t < 64; ++t) {
    float a = al[t];
    ushort4 u = *reinterpret_cast<const ushort4*>(hp + (size_t)t * H_DIM);
    acc.x += a * bf2f(u.x);
    acc.y += a * bf2f(u.y);
    acc.z += a * bf2f(u.z);
    acc.w += a * bf2f(u.w);
  }
  float* rp = r + b * H_DIM + tid * 4;
  atomicAdd(rp + 0, acc.x);
  atomicAdd(rp + 1, acc.y);
  atomicAdd(rp + 2, acc.z);
  atomicAdd(rp + 3, acc.w);
}

// ---------------- dst[i,h] = bias[h] + src_row_i . W[h,:] ----------------
// grid (H/64, B) = 1024 blocks; 4 lanes split K per output h; shfl-reduce.
__global__ void rowvec_matT_kernel(const float* __restrict__ src, size_t src_stride,
                                   const float* __restrict__ W, const float* __restrict__ bias,
                                   float* __restrict__ dst) {
  __shared__ float sv[H_DIM];
  const int i = blockIdx.y, h0 = blockIdx.x * 64, tid = threadIdx.x;
  reinterpret_cast<float4*>(sv)[tid] =
      reinterpret_cast<const float4*>(src + (size_t)i * src_stride)[tid];
  __syncthreads();
  const int hl = tid >> 2;        // 0..63
  const int kq = tid & 3;         // K quarter
  const float* wr = W + (size_t)(h0 + hl) * H_DIM + kq * 256;
  const float* svp = sv + kq * 256;
  float acc = 0.f;
#pragma unroll 4
  for (int k = 0; k < 256; k += 4) {
    float4 w4 = *reinterpret_cast<const float4*>(wr + k);
    float4 s4 = *reinterpret_cast<const float4*>(svp + k);
    acc += w4.x * s4.x + w4.y * s4.y + w4.z * s4.z + w4.w * s4.w;
  }
  acc += __shfl_xor(acc, 1, 4);
  acc += __shfl_xor(acc, 2, 4);
  if (kq == 0) dst[(size_t)i * H_DIM + h0 + hl] = acc + bias[h0 + hl];
}

// ---------------- out[i,j,h] = tanh(rp[i,h] + xq[j,h])  [B,B,H] quirk ----------------
__global__ void final_kernel(const float* __restrict__ rp, const float* __restrict__ xq,
                             float* __restrict__ out) {
  int idx = blockIdx.x * 256 + threadIdx.x;  // one float4 each
  int e = idx * 4;
  int i = e >> 16;
  int j = (e >> 10) & 63;
  int h = e & 1023;
  float4 a = *reinterpret_cast<const float4*>(&rp[i * H_DIM + h]);
  float4 b = *reinterpret_cast<const float4*>(&xq[j * H_DIM + h]);
  float4 o;
  o.x = tanh_fast(a.x + b.x);
  o.y = tanh_fast(a.y + b.y);
  o.z = tanh_fast(a.z + b.z);
  o.w = tanh_fast(a.w + b.w);
  *reinterpret_cast<float4*>(&out[e]) = o;
}

extern "C" void kernel_launch(void* const* d_in, const int* in_sizes, int n_in,
                              void* d_out, int out_size, void* d_ws, size_t ws_size,
                              hipStream_t stream) {
  const float* hidden = (const float*)d_in[0];
  // aspect (1), W_v (4), b_v (5), w_b (7) cancel under softmax -> unused
  const float* W_h = (const float*)d_in[2];
  const float* b_h = (const float*)d_in[3];
  const float* w_w = (const float*)d_in[6];  // use first H entries
  const float* W_p = (const float*)d_in[8];
  const float* b_p = (const float*)d_in[9];
  const float* W_x = (const float*)d_in[10];
  const float* b_x = (const float*)d_in[11];
  float* out = (float*)d_out;

  char* ws = (char*)d_ws;
  __bf16* hidBf = (__bf16*)ws;                  // 64 MB
  __bf16* whBf = (__bf16*)(ws + 67108864);      // 2 MB
  float* scores = (float*)(ws + 69206016);      // 128 KB
  float* r = (float*)(ws + 69468160);           // 256 KB
  float* rp = (float*)(ws + 69730304);          // 256 KB
  float* xq = (float*)(ws + 69992448);          // 256 KB

  // 1) cvt hidden; cvt W_h + zero scores/r (folded; 1024+32+64 = 1120 blocks)
  cvt_hidden_kernel<<<M_DIM * H_DIM / 1024, 256, 0, stream>>>(hidden, hidBf);
  cvtW_zero_kernel<<<1120, 256, 0, stream>>>(W_h, whBf, scores, r);

  // 2) fused GEMM -> scores (256x128 tiles, 1024 blocks, XCD-swizzled)
  gemm_scores_kernel<<<1024, 256, 0, stream>>>(hidBf, whBf, b_h, w_w, scores);

  // 3) softmax + weighted sum (fused, 512 blocks)
  wsum_kernel<<<512, 256, 0, stream>>>(scores, hidBf, r);

  // 4) rp = r @ W_p^T + b_p ; xq = hidden[:,-1,:] @ W_x^T + b_x
  rowvec_matT_kernel<<<dim3(H_DIM / 64, B_DIM), 256, 0, stream>>>(r, (size_t)H_DIM, W_p, b_p, rp);
  rowvec_matT_kernel<<<dim3(H_DIM / 64, B_DIM), 256, 0, stream>>>(
      hidden + (size_t)(T_DIM - 1) * H_DIM, (size_t)T_DIM * H_DIM, W_x, b_x, xq);

  // 5) out[i,j,h] = tanh(rp[i,h] + xq[j,h])
  final_kernel<<<(B_DIM * B_DIM * H_DIM / 4) / 256, 256, 0, stream>>>(rp, xq, out);
}